// Round 9
// baseline (236.613 us; speedup 1.0000x reference)
//
#include <hip/hip_runtime.h>
#include <hip/hip_bf16.h>
#include <cstdint>

typedef float f32x4 __attribute__((ext_vector_type(4)));
typedef short bf16x8 __attribute__((ext_vector_type(8)));

__device__ __forceinline__ unsigned short f32_to_bf16_rne(float f) {
  unsigned int u = __float_as_uint(f);
  return (unsigned short)((u + 0x7FFFu + ((u >> 16) & 1u)) >> 16);
}

#define GLOAD_LDS16(gptr, lptr)                                                             \
  __builtin_amdgcn_global_load_lds((const __attribute__((address_space(1))) unsigned int*)(gptr), \
                                   (__attribute__((address_space(3))) unsigned int*)(lptr), 16, 0, 0)

// ---------------- fused f32 -> bf16 for all 5 operands (8 elems / thread) ----------------
__global__ __launch_bounds__(256) void cvt_all(const float* __restrict__ wv,
                                               const float* __restrict__ q,
                                               const float* __restrict__ v,
                                               const float* __restrict__ wq,
                                               const float* __restrict__ wo,
                                               unsigned short* __restrict__ wvb,
                                               unsigned short* __restrict__ qb,
                                               unsigned short* __restrict__ vb,
                                               unsigned short* __restrict__ wqb,
                                               unsigned short* __restrict__ wob) {
  int i = blockIdx.x * 256 + threadIdx.x;  // chunk of 8 floats
  const float* src;
  unsigned short* dst;
  int off;
  if (i < 4194304)      { src = wv; dst = wvb; off = i; }
  else if (i < 4456448) { src = q;  dst = qb;  off = i - 4194304; }
  else if (i < 4718592) { src = v;  dst = vb;  off = i - 4456448; }
  else if (i < 4849664) { src = wq; dst = wqb; off = i - 4718592; }
  else                  { src = wo; dst = wob; off = i - 4849664; }
  const float4* s = (const float4*)src;
  float4 a = s[2 * off], b = s[2 * off + 1];
  uint4 o;
  o.x = (unsigned)f32_to_bf16_rne(a.x) | ((unsigned)f32_to_bf16_rne(a.y) << 16);
  o.y = (unsigned)f32_to_bf16_rne(a.z) | ((unsigned)f32_to_bf16_rne(a.w) << 16);
  o.z = (unsigned)f32_to_bf16_rne(b.x) | ((unsigned)f32_to_bf16_rne(b.y) << 16);
  o.w = (unsigned)f32_to_bf16_rne(b.z) | ((unsigned)f32_to_bf16_rne(b.w) << 16);
  ((uint4*)dst)[off] = o;
}

// ---------------- fuzzy membership + softmax: LDS-staged rules, one head per block --------
__global__ __launch_bounds__(256) void fuzzy2_k(const float* __restrict__ qf,
                                                const float* __restrict__ rk,
                                                const float* __restrict__ rw,
                                                float* __restrict__ attn) {
  __shared__ float lk[32][65];
  __shared__ float lc[32][65];
  const int tid = threadIdx.x;
  const int h = blockIdx.y;
  const int mbase = blockIdx.x * 128;

  for (int idx = tid; idx < 2048; idx += 256) {
    int r = idx >> 6, d = idx & 63;
    lk[r][d] = rk[(size_t)(h * 32 + r) * 64 + d];
    float w = rw[(size_t)(h * 32 + r) * 64 + d];
    lc[r][d] = 0.0078125f / (w * w);
  }
  __syncthreads();

  const int g = tid >> 5;
  const int r = tid & 31;
#pragma unroll 1
  for (int it = 0; it < 16; ++it) {
    int m = mbase + it * 8 + g;
    const float* qrow = qf + (size_t)m * 1024 + h * 64;
    float acc = 0.f;
#pragma unroll
    for (int d0 = 0; d0 < 64; d0 += 4) {
      float4 q4 = *(const float4*)(qrow + d0);
      const float* qp = (const float*)&q4;
#pragma unroll
      for (int j = 0; j < 4; ++j) {
        float diff = qp[j] - lk[r][d0 + j];
        acc += lc[r][d0 + j] * diff * diff;
      }
    }
    float z = -acc;
    float mx = z;
#pragma unroll
    for (int mask = 16; mask >= 1; mask >>= 1) mx = fmaxf(mx, __shfl_xor(mx, mask));
    float e = __expf(z - mx);
    float s = e;
#pragma unroll
    for (int mask = 16; mask >= 1; mask >>= 1) s += __shfl_xor(s, mask);
    attn[(size_t)m * 512 + h * 32 + r] = e / s;
  }
}

// ---------------- small bf16 GEMM (64x64 tile, 512 blocks, ~8/CU): C = (A@W^T+b)*scale ----
__global__ __launch_bounds__(256) void gemm_bt64(const unsigned short* __restrict__ A,
                                                 const unsigned short* __restrict__ W,
                                                 const float* __restrict__ bias, float scale,
                                                 int M, int N, int K, float* __restrict__ Cf) {
  constexpr int BK = 32;
  __shared__ unsigned short As[2][64 * BK];
  __shared__ unsigned short Bs[2][64 * BK];
  const int tid = threadIdx.x;
  const int wid = tid >> 6;
  const int lane = tid & 63;
  const int l15 = lane & 15;
  const int l4 = lane >> 4;
  const int bm = blockIdx.y * 64;
  const int bn = blockIdx.x * 64;
  const int wr = (wid >> 1) * 32;
  const int wc = (wid & 1) * 32;

  f32x4 acc[2][2];
#pragma unroll
  for (int i = 0; i < 2; ++i)
#pragma unroll
    for (int j = 0; j < 2; ++j) acc[i][j] = (f32x4){0.f, 0.f, 0.f, 0.f};

  const int nk = K / BK;
  auto stage = [&](int buf, int kt) {
    int c = tid;  // 256 chunks of 16B per 4KB tile
    int row = c >> 2, ch = c & 3;
    int sch = ch ^ ((row >> 1) & 3);
    GLOAD_LDS16(A + (size_t)(bm + row) * K + kt * BK + sch * 8, &As[buf][c * 8]);
    GLOAD_LDS16(W + (size_t)(bn + row) * K + kt * BK + sch * 8, &Bs[buf][c * 8]);
  };

  stage(0, 0);
  __syncthreads();

  for (int kt = 0; kt < nk; ++kt) {
    const int cur = kt & 1;
    if (kt + 1 < nk) stage(cur ^ 1, kt + 1);
    bf16x8 a[2], b[2];
#pragma unroll
    for (int mi = 0; mi < 2; ++mi) {
      int rl = wr + mi * 16 + l15;
      int ph = (rl * 64 + l4 * 16) ^ ((((unsigned)rl >> 1) & 3) << 4);
      a[mi] = *(const bf16x8*)((const char*)&As[cur][0] + ph);
    }
#pragma unroll
    for (int ni = 0; ni < 2; ++ni) {
      int rl = wc + ni * 16 + l15;
      int ph = (rl * 64 + l4 * 16) ^ ((((unsigned)rl >> 1) & 3) << 4);
      b[ni] = *(const bf16x8*)((const char*)&Bs[cur][0] + ph);
    }
#pragma unroll
    for (int mi = 0; mi < 2; ++mi)
#pragma unroll
      for (int ni = 0; ni < 2; ++ni)
        acc[mi][ni] = __builtin_amdgcn_mfma_f32_16x16x32_bf16(a[mi], b[ni], acc[mi][ni], 0, 0, 0);
    __syncthreads();
  }

#pragma unroll
  for (int mi = 0; mi < 2; ++mi) {
#pragma unroll
    for (int ni = 0; ni < 2; ++ni) {
      int gm = bm + wr + mi * 16 + l4 * 4;
      int gn = bn + wc + ni * 16 + l15;
      float bval = bias[gn];
#pragma unroll
      for (int q = 0; q < 4; ++q)
        Cf[(size_t)(gm + q) * N + gn] = (acc[mi][ni][q] + bval) * scale;
    }
  }
}

// ---------------- GEMM2: 256x256 tile, BK=32 slabs, 8-phase-template schedule -------------
// A: value bf16 (2048 x 1024), W: Wv bf16 (32768 x 1024)
// X[b,h,s,d] = scale * sum_r attn[m,h,r] * (A[m,:]@W[h*2048+d*32+r,:] + bias)
// Schedule (m201 template, 2 phases per K32 slab):
//   p0: read b[0..3] + a[mh0, 0..3]; issue stageA(T+2); bar; lgk0; 16 MFMA (acc[0..3]); bar
//   p1: read a[mh1, 0..3];           issue stageB(T+2); vmcnt(4); bar; lgk0; 16 MFMA; bar
// vmcnt audit: 2 loads per half-stage, 4 per slab. At slab T p1: queue = slab T+1's 4
// (old) + slab T+2's 4 (new) -> vmcnt(4) waits exactly slab T+1 (read next). Slabs 30/31
// stage nothing and use vmcnt(0). Buf reuse distance 4 slabs; reads of slab X drain at
// slab X's lgk0, stage(X+4) issues during X+2 -> no WAR race.
__global__ __launch_bounds__(512) void gemm2_k(const unsigned short* __restrict__ A,
                                               const unsigned short* __restrict__ W,
                                               const float* __restrict__ bias, float scale,
                                               const float* __restrict__ attn,
                                               unsigned short* __restrict__ X) {
  constexpr int K = 1024, BK = 32;
  extern __shared__ unsigned short lds[];  // A: 4 slabs x 8192, B: 4 x 8192 = 128 KB
  unsigned short* Asl = lds;
  unsigned short* Bsl = lds + 4 * 8192;
  const int tid = threadIdx.x;
  const int wid = tid >> 6, lane = tid & 63;
  const int l15 = lane & 15, l4 = lane >> 4;
  const int wm = wid >> 2, wn = wid & 3;  // wave tile 128x64

  // XCD-aware bijective swizzle: contiguous col-tile strip per XCD (B-panel L2 reuse)
  int orig = blockIdx.x;
  int swz = (orig & 7) * 128 + (orig >> 3);
  const int bm = (swz & 7) * 256, bn = (swz >> 3) * 256;

  auto stageA = [&](int buf, int kt) {
#pragma unroll
    for (int i = 0; i < 2; ++i) {
      int c = i * 512 + tid;  // 1024 chunks of 16B; slab = 256 rows x 4 chunks
      int row = c >> 2, ch = c & 3;
      int sch = ch ^ ((row >> 1) & 3);  // inverse swizzle on SOURCE (rule #21)
      GLOAD_LDS16(A + (size_t)(bm + row) * K + kt * BK + sch * 8, Asl + buf * 8192 + c * 8);
    }
  };
  auto stageB = [&](int buf, int kt) {
#pragma unroll
    for (int i = 0; i < 2; ++i) {
      int c = i * 512 + tid;
      int row = c >> 2, ch = c & 3;
      int sch = ch ^ ((row >> 1) & 3);
      GLOAD_LDS16(W + (size_t)(bn + row) * K + kt * BK + sch * 8, Bsl + buf * 8192 + c * 8);
    }
  };

  f32x4 acc[8][4];
#pragma unroll
  for (int i = 0; i < 8; ++i)
#pragma unroll
    for (int j = 0; j < 4; ++j) acc[i][j] = (f32x4){0.f, 0.f, 0.f, 0.f};

  bf16x8 a[4], b[4];

#define FRAG_PH(rl) (((rl) * 64 + l4 * 16) ^ ((((unsigned)(rl) >> 1) & 3) << 4))

  // phase 0 of slab in buf CB: read b + a(mh0), stage A(T+2) into SB, 16 MFMA -> acc[0..3]
#define PHASE0(CB, SB, KT, DO_ST)                                                         \
  do {                                                                                    \
    const char* _ab = (const char*)(Asl + (CB) * 8192);                                   \
    const char* _bb = (const char*)(Bsl + (CB) * 8192);                                   \
    _Pragma("unroll") for (int nf = 0; nf < 4; ++nf)                                      \
      b[nf] = *(const bf16x8*)(_bb + FRAG_PH(wn * 64 + nf * 16 + l15));                   \
    _Pragma("unroll") for (int mf = 0; mf < 4; ++mf)                                      \
      a[mf] = *(const bf16x8*)(_ab + FRAG_PH(wm * 128 + mf * 16 + l15));                  \
    if (DO_ST) stageA(SB, KT);                                                            \
    __builtin_amdgcn_s_barrier();                                                         \
    asm volatile("s_waitcnt lgkmcnt(0)" ::: "memory");                                    \
    __builtin_amdgcn_sched_barrier(0);                                                    \
    __builtin_amdgcn_s_setprio(1);                                                        \
    _Pragma("unroll") for (int mf = 0; mf < 4; ++mf)                                      \
      _Pragma("unroll") for (int nf = 0; nf < 4; ++nf)                                    \
        acc[mf][nf] =                                                                     \
            __builtin_amdgcn_mfma_f32_16x16x32_bf16(a[mf], b[nf], acc[mf][nf], 0, 0, 0);  \
    __builtin_amdgcn_s_setprio(0);                                                        \
    __builtin_amdgcn_s_barrier();                                                         \
  } while (0)

  // phase 1: read a(mh1), stage B(T+2), counted vmcnt, 16 MFMA -> acc[4..7] (b reused)
#define PHASE1(CB, SB, KT, DO_ST, WN)                                                     \
  do {                                                                                    \
    const char* _ab = (const char*)(Asl + (CB) * 8192);                                   \
    _Pragma("unroll") for (int mf = 0; mf < 4; ++mf)                                      \
      a[mf] = *(const bf16x8*)(_ab + FRAG_PH(wm * 128 + 64 + mf * 16 + l15));             \
    if (DO_ST) stageB(SB, KT);                                                            \
    asm volatile("s_waitcnt vmcnt(" #WN ")" ::: "memory");                                \
    __builtin_amdgcn_s_barrier();                                                         \
    asm volatile("s_waitcnt lgkmcnt(0)" ::: "memory");                                    \
    __builtin_amdgcn_sched_barrier(0);                                                    \
    __builtin_amdgcn_s_setprio(1);                                                        \
    _Pragma("unroll") for (int mf = 0; mf < 4; ++mf)                                      \
      _Pragma("unroll") for (int nf = 0; nf < 4; ++nf)                                    \
        acc[4 + mf][nf] =                                                                 \
            __builtin_amdgcn_mfma_f32_16x16x32_bf16(a[mf], b[nf], acc[4 + mf][nf], 0, 0, 0); \
    __builtin_amdgcn_s_setprio(0);                                                        \
    __builtin_amdgcn_s_barrier();                                                         \
  } while (0)

  // prologue: stage slabs 0,1 (8 loads); vmcnt(4) -> slab 0 landed, slab 1 in flight
  stageA(0, 0); stageB(0, 0);
  stageA(1, 1); stageB(1, 1);
  asm volatile("s_waitcnt vmcnt(4)" ::: "memory");
  __builtin_amdgcn_s_barrier();

  // slabs 0..29: stage slab T+2, counted vmcnt(4)
  for (int T = 0; T < 30; ++T) {
    const int cb = T & 3, sb = (T + 2) & 3;
    PHASE0(cb, sb, T + 2, 1);
    PHASE1(cb, sb, T + 2, 1, 4);
  }
  // slab 30: no stage; vmcnt(0) drains slab 31's loads before slab-31 reads
  PHASE0(2, 0, 0, 0);
  PHASE1(2, 0, 0, 0, 0);
  // slab 31: no stage, nothing outstanding
  PHASE0(3, 0, 0, 0);
  PHASE1(3, 0, 0, 0, 0);
#undef PHASE0
#undef PHASE1
#undef FRAG_PH

  // ---- fused rule-aggregation epilogue (per-mf to bound register pressure) ----
  const int h = bn >> 11;                          // 2048 cols per head
  const int dbase = ((bn & 2047) + wn * 64) >> 5;  // even
#pragma unroll
  for (int mf = 0; mf < 8; ++mf) {
    int gm0 = bm + wm * 128 + mf * 16 + l4 * 4;
    float red[4][2];
#pragma unroll
    for (int q = 0; q < 4; ++q) { red[q][0] = 0.f; red[q][1] = 0.f; }
#pragma unroll
    for (int nf = 0; nf < 4; ++nf) {
      int col = bn + wn * 64 + nf * 16 + l15;
      float bval = bias[col];
      int r = (nf & 1) * 16 + l15;
      int g = nf >> 1;
#pragma unroll
      for (int q = 0; q < 4; ++q) {
        float w = attn[(size_t)(gm0 + q) * 512 + h * 32 + r];
        red[q][g] += (acc[mf][nf][q] + bval) * w;
      }
    }
#pragma unroll
    for (int q = 0; q < 4; ++q)
#pragma unroll
      for (int g = 0; g < 2; ++g) {
        float vv = red[q][g];
        for (int mask = 1; mask < 16; mask <<= 1) vv += __shfl_xor(vv, mask);
        red[q][g] = vv * scale;
      }
    if (l15 == 0) {
#pragma unroll
      for (int q = 0; q < 4; ++q) {
        int m = gm0 + q;
        int bb = m >> 10, s = m & 1023;
        size_t base = (((size_t)(bb * 16 + h)) * 1024 + s) * 64;
        unsigned lo = f32_to_bf16_rne(red[q][0]);
        unsigned hi = f32_to_bf16_rne(red[q][1]);
        ((unsigned*)X)[(base + dbase) >> 1] = lo | (hi << 16);
      }
    }
  }
}

extern "C" void kernel_launch(void* const* d_in, const int* in_sizes, int n_in, void* d_out,
                              int out_size, void* d_ws, size_t ws_size, hipStream_t stream) {
  const float* query = (const float*)d_in[0];
  const float* value = (const float*)d_in[2];
  const float* rk = (const float*)d_in[3];
  const float* rw = (const float*)d_in[4];
  const float* Wq = (const float*)d_in[5];
  const float* bq = (const float*)d_in[6];
  const float* Wv = (const float*)d_in[7];
  const float* bv = (const float*)d_in[8];
  const float* Wo = (const float*)d_in[9];
  const float* bo = (const float*)d_in[10];
  float* out = (float*)d_out;

  const float scale = 0.125f;

  char* p = (char*)d_ws;
  unsigned short* Wv_b = (unsigned short*)p; p += (size_t)33554432 * 2;
  unsigned short* Aq_b = (unsigned short*)p; p += (size_t)2097152 * 2;
  unsigned short* Av_b = (unsigned short*)p; p += (size_t)2097152 * 2;
  unsigned short* Wq_b = (unsigned short*)p; p += (size_t)1048576 * 2;
  unsigned short* Wo_b = (unsigned short*)p; p += (size_t)1048576 * 2;
  float* qf = (float*)p;   p += (size_t)2097152 * 4;
  float* attn = (float*)p; p += (size_t)1048576 * 4;
  unsigned short* X = (unsigned short*)p;

  cvt_all<<<19456, 256, 0, stream>>>(Wv, query, value, Wq, Wo, Wv_b, Aq_b, Av_b, Wq_b, Wo_b);

  // GEMM1: qf = (query @ Wq^T + bq) * scale   (2048 x 1024), 512 blocks
  gemm_bt64<<<dim3(16, 32), 256, 0, stream>>>(Aq_b, Wq_b, bq, scale, 2048, 1024, 1024, qf);
  // fuzzy membership + softmax
  fuzzy2_k<<<dim3(16, 16), 256, 0, stream>>>(qf, rk, rw, attn);
  // GEMM2 fused (256^2, 8-phase-template schedule, 128KB dynamic LDS)
  hipFuncSetAttribute((const void*)gemm2_k, hipFuncAttributeMaxDynamicSharedMemorySize, 131072);
  gemm2_k<<<1024, 512, 131072, stream>>>(Av_b, Wv_b, bv, scale, attn, X);
  // GEMM3: out = X @ Wo^T + bo
  gemm_bt64<<<dim3(16, 32), 256, 0, stream>>>(X, Wo_b, bo, 1.0f, 2048, 1024, 1024, out);
}